// Round 1
// baseline (202.927 us; speedup 1.0000x reference)
//
#include <hip/hip_runtime.h>

#define NTOK 8192
#define DDIM 1024
#define NEXP 16
#define NPAIR 136  // E*(E+1)/2 pairs with e<=f

// ---------------------------------------------------------------------------
// Fused kernel: router (gemv vs LDS-staged gate_w) + top2 + weighted combine
// with shared experts + column sum of x^2 (for diversity loss).
// One wave (64 lanes) per token; lane l owns d = 4l + 256j (+0..3), j=0..3.
// ---------------------------------------------------------------------------
__global__ __launch_bounds__(256) void moe_fused(
    const float* __restrict__ x,
    const float* __restrict__ gate_w,
    const float* __restrict__ gate_b,
    const float* __restrict__ sh,
    const float* __restrict__ re,
    float* __restrict__ out,
    float* __restrict__ s_glob)
{
    __shared__ float gwl[NEXP * DDIM];   // 64 KB gate weights
    __shared__ float gbl[NEXP];
    __shared__ float s_part[DDIM];       // per-block partial of sum_n x^2

    const int t = threadIdx.x;

    // stage gate_w into LDS (4096 float4, coalesced)
    {
        const float4* gw4 = (const float4*)gate_w;
        float4* gl4 = (float4*)gwl;
        for (int i = t; i < NEXP * DDIM / 4; i += 256) gl4[i] = gw4[i];
    }
    if (t < NEXP) gbl[t] = gate_b[t];
    ((float4*)s_part)[t] = make_float4(0.f, 0.f, 0.f, 0.f);  // 256 thr * 4 = 1024
    __syncthreads();

    const int lane = t & 63;
    const int wid = (blockIdx.x << 2) + (t >> 6);
    const int nwaves = gridDim.x << 2;

    // hoist shared-expert column sum for this lane's d-slots
    float4 shs[4];
    {
        const float4* s0 = (const float4*)sh;
        const float4* s1 = (const float4*)(sh + DDIM);
        #pragma unroll
        for (int j = 0; j < 4; ++j) {
            float4 a = s0[lane + 64 * j];
            float4 b = s1[lane + 64 * j];
            shs[j] = make_float4(a.x + b.x, a.y + b.y, a.z + b.z, a.w + b.w);
        }
    }

    float4 ssum[4];
    #pragma unroll
    for (int j = 0; j < 4; ++j) ssum[j] = make_float4(0.f, 0.f, 0.f, 0.f);

    for (int n = wid; n < NTOK; n += nwaves) {
        const float4* xr = (const float4*)(x + (size_t)n * DDIM);
        float4 xv[4];
        #pragma unroll
        for (int j = 0; j < 4; ++j) xv[j] = xr[lane + 64 * j];

        // 16 gate dot-products, per-lane partials over this lane's 16 d's
        float acc[NEXP];
        #pragma unroll
        for (int e = 0; e < NEXP; ++e) acc[e] = 0.f;
        #pragma unroll
        for (int e = 0; e < NEXP; ++e) {
            const float4* g4 = (const float4*)(gwl + e * DDIM);
            #pragma unroll
            for (int j = 0; j < 4; ++j) {
                float4 g = g4[lane + 64 * j];
                acc[e] += xv[j].x * g.x + xv[j].y * g.y + xv[j].z * g.z + xv[j].w * g.w;
            }
        }
        // full-wave butterfly reduce: every lane ends with all 16 logits
        #pragma unroll
        for (int off = 32; off >= 1; off >>= 1) {
            #pragma unroll
            for (int e = 0; e < NEXP; ++e)
                acc[e] += __shfl_xor(acc[e], off, 64);
        }

        // top-2 (first-index tie-break, matches jax.lax.top_k) on logits+bias
        float v0 = -3.0e38f, v1 = -3.0e38f;
        int i0 = 0, i1 = 0;
        #pragma unroll
        for (int e = 0; e < NEXP; ++e) {
            float lg = acc[e] + gbl[e];
            if (lg > v0) { i0 = e; v0 = lg; }
        }
        #pragma unroll
        for (int e = 0; e < NEXP; ++e) {
            float lg = acc[e] + gbl[e];
            if (e != i0 && lg > v1) { i1 = e; v1 = lg; }
        }
        // softmax denominator cancels in weight normalization:
        float ex = expf(v1 - v0);          // <= 1
        float inv = 1.f / (1.f + ex);
        float w0 = inv;
        float w1 = ex * inv;

        const float4* r0 = (const float4*)(re + (size_t)i0 * DDIM);
        const float4* r1 = (const float4*)(re + (size_t)i1 * DDIM);
        float4* o = (float4*)(out + (size_t)n * DDIM);
        #pragma unroll
        for (int j = 0; j < 4; ++j) {
            float4 a = r0[lane + 64 * j];
            float4 b = r1[lane + 64 * j];
            float4 xj = xv[j];
            float4 r;
            r.x = xj.x * (shs[j].x + w0 * a.x + w1 * b.x);
            r.y = xj.y * (shs[j].y + w0 * a.y + w1 * b.y);
            r.z = xj.z * (shs[j].z + w0 * a.z + w1 * b.z);
            r.w = xj.w * (shs[j].w + w0 * a.w + w1 * b.w);
            o[lane + 64 * j] = r;
            ssum[j].x = fmaf(xj.x, xj.x, ssum[j].x);
            ssum[j].y = fmaf(xj.y, xj.y, ssum[j].y);
            ssum[j].z = fmaf(xj.z, xj.z, ssum[j].z);
            ssum[j].w = fmaf(xj.w, xj.w, ssum[j].w);
        }
    }

    // block-level reduce of x^2 column sums, then one global atomic per d
    #pragma unroll
    for (int j = 0; j < 4; ++j) {
        int base = 4 * lane + 256 * j;
        atomicAdd(&s_part[base + 0], ssum[j].x);
        atomicAdd(&s_part[base + 1], ssum[j].y);
        atomicAdd(&s_part[base + 2], ssum[j].z);
        atomicAdd(&s_part[base + 3], ssum[j].w);
    }
    __syncthreads();
    {
        float4 v = ((float4*)s_part)[t];
        atomicAdd(&s_glob[4 * t + 0], v.x);
        atomicAdd(&s_glob[4 * t + 1], v.y);
        atomicAdd(&s_glob[4 * t + 2], v.z);
        atomicAdd(&s_glob[4 * t + 3], v.w);
    }
}

// ---------------------------------------------------------------------------
// Diversity loss tail: G[e,f] = sum_d s[d]*re[e,d]*re[f,d]; cosine sims.
// Single block of 1024 threads: 4 threads per (e<=f) pair.
// ---------------------------------------------------------------------------
__global__ __launch_bounds__(1024) void moe_div(
    const float* __restrict__ re,
    const float* __restrict__ s_glob,
    float* __restrict__ div_out)
{
    __shared__ float rel[NEXP * 1025];   // +1 pad breaks bank aliasing
    __shared__ float sl[DDIM];
    __shared__ float Gl[NPAIR];

    const int t = threadIdx.x;
    for (int i = t; i < NEXP * DDIM; i += 1024) {
        int e = i >> 10, d = i & 1023;
        rel[e * 1025 + d] = re[i];
    }
    sl[t] = s_glob[t];
    __syncthreads();

    const int p = t >> 2;     // pair id, 0..255 (>=136 idle)
    const int sub = t & 3;
    float a = 0.f;
    if (p < NPAIR) {
        int e = 0, rem = p;
        while (rem >= NEXP - e) { rem -= NEXP - e; ++e; }
        int f = e + rem;
        const float* r0 = rel + e * 1025;
        const float* r1 = rel + f * 1025;
        #pragma unroll 8
        for (int i = 0; i < 256; ++i) {
            int d = sub + 4 * i;
            a += sl[d] * r0[d] * r1[d];
        }
    }
    a += __shfl_down(a, 2, 64);
    a += __shfl_down(a, 1, 64);
    if (p < NPAIR && sub == 0) Gl[p] = a;
    __syncthreads();

    if (t == 0) {
        float nr[NEXP];
        #pragma unroll
        for (int e = 0; e < NEXP; ++e) {
            int idx = e * NEXP - (e * (e - 1)) / 2;   // index of (e,e)
            nr[e] = fmaxf(sqrtf(Gl[idx]), 1e-8f);
        }
        float sum = 0.f;
        for (int e = 0; e < NEXP; ++e) {
            int base = e * NEXP - (e * (e - 1)) / 2;
            for (int f = e + 1; f < NEXP; ++f) {
                float sim = Gl[base + (f - e)] / (nr[e] * nr[f]);
                sim = fminf(1.f, fmaxf(-1.f, sim));
                sum += 2.f * sim;                     // (e,f) and (f,e)
            }
        }
        *div_out = sum / (float)(NEXP * (NEXP - 1)) * 0.1f;
    }
}

extern "C" void kernel_launch(void* const* d_in, const int* in_sizes, int n_in,
                              void* d_out, int out_size, void* d_ws, size_t ws_size,
                              hipStream_t stream) {
    const float* x  = (const float*)d_in[0];
    const float* gw = (const float*)d_in[1];
    const float* gb = (const float*)d_in[2];
    const float* sh = (const float*)d_in[3];
    const float* re = (const float*)d_in[4];
    float* out = (float*)d_out;
    float* s_glob = (float*)d_ws;   // 1024 floats of scratch

    hipMemsetAsync(s_glob, 0, DDIM * sizeof(float), stream);
    // LDS = 64KB gate + 4KB s_part -> 2 blocks/CU; 512 blocks fills 256 CUs.
    moe_fused<<<512, 256, 0, stream>>>(x, gw, gb, sh, re, out, s_glob);
    moe_div<<<1, 1024, 0, stream>>>(re, s_glob, out + (size_t)NTOK * DDIM);
}

// Round 2
// 185.392 us; speedup vs baseline: 1.0946x; 1.0946x over previous
//
#include <hip/hip_runtime.h>

#define NTOK 8192
#define DDIM 1024
#define NEXP 16
#define GROW 1028   // gate LDS row stride (pad 4 floats -> 2-way bank alias, free)
#define NPAIR 136   // E*(E+1)/2 pairs e<=f

// ---------------------------------------------------------------------------
// Fused: router + top2 + weighted combine + x^2 column-sum.
// Wave = 4 token-groups x 16 experts. Lane (g,e) computes the FULL logit for
// expert e of token n0+g (no cross-lane reduction). Gate rows in LDS
// (broadcast across groups), x via 16-lane-broadcast global loads (L1-served).
// ---------------------------------------------------------------------------
__global__ __launch_bounds__(256) void moe_fused(
    const float* __restrict__ x,
    const float* __restrict__ gate_w,
    const float* __restrict__ gate_b,
    const float* __restrict__ sh,
    const float* __restrict__ re,
    float* __restrict__ out,
    float* __restrict__ s_glob)
{
    __shared__ float gwl[NEXP * GROW];
    __shared__ float gbl[NEXP];
    __shared__ float s_part[DDIM];

    const int t = threadIdx.x;

    // stage gate_w into padded LDS rows (float4)
    {
        const float4* gw4 = (const float4*)gate_w;
        for (int i = t; i < NEXP * DDIM / 4; i += 256) {
            int e = i >> 8, d4 = i & 255;
            ((float4*)(gwl + e * GROW))[d4] = gw4[i];
        }
    }
    if (t < NEXP) gbl[t] = gate_b[t];
    ((float4*)s_part)[t] = make_float4(0.f, 0.f, 0.f, 0.f);
    __syncthreads();

    const int lane = t & 63;
    const int e = lane & 15;
    const int g = lane >> 4;
    const int wid = (blockIdx.x << 2) + (t >> 6);   // 0..2047
    const int n0 = wid << 2;                        // 4 contiguous tokens

    // hoisted shared-expert column sum for this lane's combine slots
    float4 shs[4];
    {
        const float4* s0 = (const float4*)sh;
        const float4* s1 = (const float4*)(sh + DDIM);
        #pragma unroll
        for (int j = 0; j < 4; ++j) {
            float4 a = s0[lane + 64 * j];
            float4 b = s1[lane + 64 * j];
            shs[j] = make_float4(a.x + b.x, a.y + b.y, a.z + b.z, a.w + b.w);
        }
    }

    // ---- routing: lane computes logit(token n0+g, expert e) over all d ----
    const float4* xr = (const float4*)(x + (size_t)(n0 + g) * DDIM);
    const float4* gr = (const float4*)(gwl + e * GROW);
    float4 a4 = make_float4(0.f, 0.f, 0.f, 0.f);
    #pragma unroll 8
    for (int i = 0; i < 256; ++i) {
        float4 xv = xr[i];          // broadcast within 16-lane group
        float4 gv = gr[i];          // ds_read_b128, 16 addrs, 2-way alias
        a4.x = fmaf(xv.x, gv.x, a4.x);
        a4.y = fmaf(xv.y, gv.y, a4.y);
        a4.z = fmaf(xv.z, gv.z, a4.z);
        a4.w = fmaf(xv.w, gv.w, a4.w);
    }
    float acc = (a4.x + a4.y) + (a4.z + a4.w) + gbl[e];

    // ---- top2 scan within the 16-lane group (stable, matches lax.top_k) ----
    float v0 = -3.0e38f, v1 = -3.0e38f;
    int i0 = 0, i1 = 0;
    const int base = lane & 48;
    #pragma unroll
    for (int j = 0; j < 16; ++j) {
        float lv = __shfl(acc, base + j, 64);
        if (lv > v0)      { v1 = v0; i1 = i0; v0 = lv; i0 = j; }
        else if (lv > v1) { v1 = lv; i1 = j; }
    }
    // softmax denom cancels in the top-2 renormalization:
    float ex = __expf(v1 - v0);          // <= 1
    float w0 = 1.f / (1.f + ex);
    float w1 = ex * w0;

    float4 ssum[4];
    #pragma unroll
    for (int j = 0; j < 4; ++j) ssum[j] = make_float4(0.f, 0.f, 0.f, 0.f);

    // ---- combine: whole wave per token, coalesced float4 ----
    #pragma unroll
    for (int tk = 0; tk < 4; ++tk) {
        const int src = tk << 4;
        float a0 = __shfl(w0, src, 64);
        float a1 = __shfl(w1, src, 64);
        int   e0 = __shfl(i0, src, 64);
        int   e1 = __shfl(i1, src, 64);
        const float4* xrow = (const float4*)(x + (size_t)(n0 + tk) * DDIM);
        const float4* r0 = (const float4*)(re + (size_t)e0 * DDIM);
        const float4* r1 = (const float4*)(re + (size_t)e1 * DDIM);
        float4* o = (float4*)(out + (size_t)(n0 + tk) * DDIM);
        #pragma unroll
        for (int j = 0; j < 4; ++j) {
            float4 xv = xrow[lane + 64 * j];
            float4 b0 = r0[lane + 64 * j];
            float4 b1 = r1[lane + 64 * j];
            float4 r;
            r.x = xv.x * (shs[j].x + a0 * b0.x + a1 * b1.x);
            r.y = xv.y * (shs[j].y + a0 * b0.y + a1 * b1.y);
            r.z = xv.z * (shs[j].z + a0 * b0.z + a1 * b1.z);
            r.w = xv.w * (shs[j].w + a0 * b0.w + a1 * b1.w);
            o[lane + 64 * j] = r;
            ssum[j].x = fmaf(xv.x, xv.x, ssum[j].x);
            ssum[j].y = fmaf(xv.y, xv.y, ssum[j].y);
            ssum[j].z = fmaf(xv.z, xv.z, ssum[j].z);
            ssum[j].w = fmaf(xv.w, xv.w, ssum[j].w);
        }
    }

    // block-level reduce of x^2 partials, then one global atomic per d
    #pragma unroll
    for (int j = 0; j < 4; ++j) {
        int b = 4 * lane + 256 * j;
        atomicAdd(&s_part[b + 0], ssum[j].x);
        atomicAdd(&s_part[b + 1], ssum[j].y);
        atomicAdd(&s_part[b + 2], ssum[j].z);
        atomicAdd(&s_part[b + 3], ssum[j].w);
    }
    __syncthreads();
    {
        float4 v = ((float4*)s_part)[t];
        atomicAdd(&s_glob[4 * t + 0], v.x);
        atomicAdd(&s_glob[4 * t + 1], v.y);
        atomicAdd(&s_glob[4 * t + 2], v.z);
        atomicAdd(&s_glob[4 * t + 3], v.w);
    }
}

// ---------------------------------------------------------------------------
// Diversity loss: G[e,f] = sum_d s[d]*re[e,d]*re[f,d]; cosine sims.
// Parallel tail: norms by 16 threads, 120 off-diag sims + LDS-atomic reduce.
// ---------------------------------------------------------------------------
__global__ __launch_bounds__(1024) void moe_div(
    const float* __restrict__ re,
    const float* __restrict__ s_glob,
    float* __restrict__ div_out)
{
    __shared__ float rel[NEXP * 1025];
    __shared__ float sl[DDIM];
    __shared__ float Gl[NPAIR];
    __shared__ float nrl[NEXP];
    __shared__ float lsum;

    const int t = threadIdx.x;
    for (int i = t; i < NEXP * DDIM; i += 1024) {
        int e = i >> 10, d = i & 1023;
        rel[e * 1025 + d] = re[i];
    }
    sl[t] = s_glob[t];
    if (t == 0) lsum = 0.f;
    __syncthreads();

    const int p = t >> 2;     // pair id
    const int sub = t & 3;
    int pe = 0, pf = 0;
    float a = 0.f;
    if (p < NPAIR) {
        int rem = p;
        while (rem >= NEXP - pe) { rem -= NEXP - pe; ++pe; }
        pf = pe + rem;
        const float* r0 = rel + pe * 1025;
        const float* r1 = rel + pf * 1025;
        #pragma unroll 8
        for (int i = 0; i < 256; ++i) {
            int d = sub + 4 * i;
            a += sl[d] * r0[d] * r1[d];
        }
    }
    a += __shfl_down(a, 2, 64);
    a += __shfl_down(a, 1, 64);
    if (p < NPAIR && sub == 0) Gl[p] = a;
    __syncthreads();

    if (t < NEXP) {
        int idx = t * NEXP - (t * (t - 1)) / 2;    // (t,t)
        nrl[t] = fmaxf(sqrtf(Gl[idx]), 1e-8f);
    }
    __syncthreads();

    if (sub == 0 && p < NPAIR && pe != pf) {
        float sim = Gl[p] / (nrl[pe] * nrl[pf]);
        sim = fminf(1.f, fmaxf(-1.f, sim));
        atomicAdd(&lsum, 2.f * sim);
    }
    __syncthreads();
    if (t == 0) *div_out = lsum / (float)(NEXP * (NEXP - 1)) * 0.1f;
}

extern "C" void kernel_launch(void* const* d_in, const int* in_sizes, int n_in,
                              void* d_out, int out_size, void* d_ws, size_t ws_size,
                              hipStream_t stream) {
    const float* x  = (const float*)d_in[0];
    const float* gw = (const float*)d_in[1];
    const float* gb = (const float*)d_in[2];
    const float* sh = (const float*)d_in[3];
    const float* re = (const float*)d_in[4];
    float* out = (float*)d_out;
    float* s_glob = (float*)d_ws;

    hipMemsetAsync(s_glob, 0, DDIM * sizeof(float), stream);
    // LDS ~70 KB -> 2 blocks/CU; 512 blocks fill 256 CUs exactly.
    moe_fused<<<512, 256, 0, stream>>>(x, gw, gb, sh, re, out, s_glob);
    moe_div<<<1, 1024, 0, stream>>>(re, s_glob, out + (size_t)NTOK * DDIM);
}

// Round 3
// 175.642 us; speedup vs baseline: 1.1553x; 1.0555x over previous
//
#include <hip/hip_runtime.h>

#define NTOK 8192
#define DDIM 1024
#define NEXP 16
#define NPAIR 136   // E*(E+1)/2, pairs with e<=f
#define NREP 8      // s_glob replicas to spread atomic contention

// ---------------------------------------------------------------------------
// Fused: router + top2 + weighted combine + x^2 column-sum partials.
// 1024 blocks x 256 thr; wave handles 2 tokens. Lane = (g token, h d-half,
// e expert): lane computes a 512-d partial dot for (token g, expert e);
// one shfl_xor(16) completes the logit. Gate read from global (L1/L2-hot,
// 2-way broadcast over g). LDS = 4 KB only -> 16 waves/CU.
// ---------------------------------------------------------------------------
__global__ __launch_bounds__(256, 4) void moe_fused(
    const float* __restrict__ x,
    const float* __restrict__ gate_w,
    const float* __restrict__ gate_b,
    const float* __restrict__ sh,
    const float* __restrict__ re,
    float* __restrict__ out,
    float* __restrict__ s_glob)
{
    __shared__ float s_part[DDIM];

    const int t = threadIdx.x;
    ((float4*)s_part)[t] = make_float4(0.f, 0.f, 0.f, 0.f);
    __syncthreads();

    const int lane = t & 63;
    const int e = lane & 15;         // expert
    const int h = (lane >> 4) & 1;   // d-half
    const int g = lane >> 5;         // token within wave
    const int wid = (blockIdx.x << 2) + (t >> 6);
    const int n0 = wid << 1;         // 2 tokens per wave

    // hoisted shared-expert column sum for combine slots (L1-served, 8 KB)
    float4 shs[4];
    {
        const float4* s0 = (const float4*)sh;
        const float4* s1 = (const float4*)(sh + DDIM);
        #pragma unroll
        for (int j = 0; j < 4; ++j) {
            float4 a = s0[lane + 64 * j];
            float4 b = s1[lane + 64 * j];
            shs[j] = make_float4(a.x + b.x, a.y + b.y, a.z + b.z, a.w + b.w);
        }
    }

    // ---- routing: 512-d partial dot per lane, gate from global ----
    const float4* x4 = (const float4*)(x + (size_t)(n0 + g) * DDIM) + h * 128;
    const float4* g4 = (const float4*)(gate_w + (size_t)e * DDIM) + h * 128;
    float4 a4 = make_float4(0.f, 0.f, 0.f, 0.f);
    #pragma unroll 8
    for (int i = 0; i < 128; ++i) {
        float4 xv = x4[i];   // 4 distinct addrs/wave (16-way broadcast)
        float4 gv = g4[i];   // 32 distinct addrs/wave (2-way broadcast)
        a4.x = fmaf(xv.x, gv.x, a4.x);
        a4.y = fmaf(xv.y, gv.y, a4.y);
        a4.z = fmaf(xv.z, gv.z, a4.z);
        a4.w = fmaf(xv.w, gv.w, a4.w);
    }
    float acc = (a4.x + a4.y) + (a4.z + a4.w);
    acc += __shfl_xor(acc, 16, 64);  // combine the two d-halves
    acc += gate_b[e];

    // ---- top2 scan within this token's 16 expert lanes (h=0 subgroup) ----
    float v0 = -3.0e38f, v1 = -3.0e38f;
    int i0 = 0, i1 = 0;
    const int base = lane & 32;
    #pragma unroll
    for (int j = 0; j < NEXP; ++j) {
        float lv = __shfl(acc, base + j, 64);
        if (lv > v0)      { v1 = v0; i1 = i0; v0 = lv; i0 = j; }
        else if (lv > v1) { v1 = lv; i1 = j; }
    }
    // softmax denominator cancels in top-2 renormalization
    float ex = __expf(v1 - v0);      // <= 1
    float w0 = 1.f / (1.f + ex);
    float w1 = ex * w0;

    float4 ssum[4];
    #pragma unroll
    for (int j = 0; j < 4; ++j) ssum[j] = make_float4(0.f, 0.f, 0.f, 0.f);

    // ---- combine: whole wave per token, coalesced float4 ----
    #pragma unroll
    for (int tk = 0; tk < 2; ++tk) {
        const int src = tk << 5;
        float a0 = __shfl(w0, src, 64);
        float a1 = __shfl(w1, src, 64);
        int   e0 = __shfl(i0, src, 64);
        int   e1 = __shfl(i1, src, 64);
        const float4* xrow = (const float4*)(x + (size_t)(n0 + tk) * DDIM);
        const float4* r0 = (const float4*)(re + (size_t)e0 * DDIM);
        const float4* r1 = (const float4*)(re + (size_t)e1 * DDIM);
        float4* o = (float4*)(out + (size_t)(n0 + tk) * DDIM);
        #pragma unroll
        for (int j = 0; j < 4; ++j) {
            float4 xv = xrow[lane + 64 * j];
            float4 b0 = r0[lane + 64 * j];
            float4 b1 = r1[lane + 64 * j];
            float4 r;
            r.x = xv.x * (shs[j].x + a0 * b0.x + a1 * b1.x);
            r.y = xv.y * (shs[j].y + a0 * b0.y + a1 * b1.y);
            r.z = xv.z * (shs[j].z + a0 * b0.z + a1 * b1.z);
            r.w = xv.w * (shs[j].w + a0 * b0.w + a1 * b1.w);
            o[lane + 64 * j] = r;
            ssum[j].x = fmaf(xv.x, xv.x, ssum[j].x);
            ssum[j].y = fmaf(xv.y, xv.y, ssum[j].y);
            ssum[j].z = fmaf(xv.z, xv.z, ssum[j].z);
            ssum[j].w = fmaf(xv.w, xv.w, ssum[j].w);
        }
    }

    // block-reduce x^2 partials in LDS, then per-thread global atomics into
    // one of NREP replicas (spreads same-address L2 atomic serialization)
    #pragma unroll
    for (int j = 0; j < 4; ++j) {
        int b = 4 * lane + 256 * j;
        atomicAdd(&s_part[b + 0], ssum[j].x);
        atomicAdd(&s_part[b + 1], ssum[j].y);
        atomicAdd(&s_part[b + 2], ssum[j].z);
        atomicAdd(&s_part[b + 3], ssum[j].w);
    }
    __syncthreads();
    {
        float* rep = s_glob + (size_t)(blockIdx.x & (NREP - 1)) * DDIM;
        float4 v = ((float4*)s_part)[t];
        atomicAdd(&rep[4 * t + 0], v.x);
        atomicAdd(&rep[4 * t + 1], v.y);
        atomicAdd(&rep[4 * t + 2], v.z);
        atomicAdd(&rep[4 * t + 3], v.w);
    }
}

// ---------------------------------------------------------------------------
// G[p] = sum_d s[d]*re[e,d]*re[f,d] over the block's 64-d chunk.
// 16 blocks x 320 threads; 2 threads per pair (32 d each).
// ---------------------------------------------------------------------------
__global__ __launch_bounds__(320) void moe_div_partial(
    const float* __restrict__ re,
    const float* __restrict__ s_glob,
    float* __restrict__ G)
{
    __shared__ float reT[64][17];    // [d][e], padded
    __shared__ float s_loc[64];

    const int t = threadIdx.x;
    const int d0 = blockIdx.x * 64;

    if (t < 64) {
        float s = 0.f;
        #pragma unroll
        for (int r = 0; r < NREP; ++r) s += s_glob[r * DDIM + d0 + t];
        s_loc[t] = s;
    }
    if (t < 256) {
        int e = t >> 4, dd4 = (t & 15) * 4;
        float4 v = ((const float4*)(re + (size_t)e * DDIM + d0))[t & 15];
        reT[dd4 + 0][e] = v.x;
        reT[dd4 + 1][e] = v.y;
        reT[dd4 + 2][e] = v.z;
        reT[dd4 + 3][e] = v.w;
    }
    __syncthreads();

    const int p = t >> 1;
    const int half = t & 1;
    float a = 0.f;
    if (p < NPAIR) {
        int pe = 0, rem = p;
        while (rem >= NEXP - pe) { rem -= NEXP - pe; ++pe; }
        int pf = pe + rem;
        #pragma unroll
        for (int i = 0; i < 32; ++i) {
            int dd = half * 32 + i;
            a += s_loc[dd] * reT[dd][pe] * reT[dd][pf];
        }
    }
    a += __shfl_down(a, 1, 64);
    if (p < NPAIR && half == 0) atomicAdd(&G[p], a);
}

// ---------------------------------------------------------------------------
// Finalize: norms from diag of G, clipped cosine sims, mean * lambda.
// ---------------------------------------------------------------------------
__global__ __launch_bounds__(64) void moe_div_final(
    const float* __restrict__ G,
    float* __restrict__ div_out)
{
    __shared__ float nr[NEXP];
    __shared__ float lsum;
    const int t = threadIdx.x;
    if (t == 0) lsum = 0.f;
    if (t < NEXP) {
        int idx = t * NEXP - (t * (t - 1)) / 2;   // (t,t) diagonal
        nr[t] = fmaxf(sqrtf(G[idx]), 1e-8f);
    }
    __syncthreads();

    float local = 0.f;
    for (int p = t; p < NPAIR; p += 64) {
        int pe = 0, rem = p;
        while (rem >= NEXP - pe) { rem -= NEXP - pe; ++pe; }
        int pf = pe + rem;
        if (pe != pf) {
            float sim = G[p] / (nr[pe] * nr[pf]);
            sim = fminf(1.f, fmaxf(-1.f, sim));
            local += 2.f * sim;                   // (e,f) and (f,e)
        }
    }
    atomicAdd(&lsum, local);
    __syncthreads();
    if (t == 0) *div_out = lsum / (float)(NEXP * (NEXP - 1)) * 0.1f;
}

extern "C" void kernel_launch(void* const* d_in, const int* in_sizes, int n_in,
                              void* d_out, int out_size, void* d_ws, size_t ws_size,
                              hipStream_t stream) {
    const float* x  = (const float*)d_in[0];
    const float* gw = (const float*)d_in[1];
    const float* gb = (const float*)d_in[2];
    const float* sh = (const float*)d_in[3];
    const float* re = (const float*)d_in[4];
    float* out = (float*)d_out;
    float* s_glob = (float*)d_ws;                  // NREP*1024 floats
    float* G = s_glob + NREP * DDIM;               // 136 floats

    hipMemsetAsync(d_ws, 0, (NREP * DDIM + NPAIR) * sizeof(float), stream);
    moe_fused<<<1024, 256, 0, stream>>>(x, gw, gb, sh, re, out, s_glob);
    moe_div_partial<<<16, 320, 0, stream>>>(re, s_glob, G);
    moe_div_final<<<1, 64, 0, stream>>>(G, out + (size_t)NTOK * DDIM);
}

// Round 4
// 124.572 us; speedup vs baseline: 1.6290x; 1.4100x over previous
//
#include <hip/hip_runtime.h>

#define NTOK 8192
#define DDIM 1024
#define NEXP 16
#define NPAIR 136   // E*(E+1)/2 pairs with e<=f
#define NREP 8      // s_glob replicas (atomic spread)
#define XROW 1032   // LDS x-tile row stride in floats (pad 8: 2-way alias only)

// ws layout (floats): gwT4 [256*16 float4] = 16384 f | s_glob [NREP*1024] | G_part [16*136]
#define WS_GWT 0
#define WS_SG  16384
#define WS_GP  (16384 + NREP * DDIM)

// ---------------------------------------------------------------------------
// Prep: transpose gate_w [16][1024] -> gwT4[d4][e] (float4 over d, expert-
// contiguous) so routing reads are fully coalesced. Also zeroes s_glob.
// ---------------------------------------------------------------------------
__global__ __launch_bounds__(256) void moe_prep(
    const float* __restrict__ gate_w,
    float* __restrict__ ws)
{
    const int gid = blockIdx.x * 256 + threadIdx.x;   // 0..4095
    const int e = gid & 15;
    const int d4 = gid >> 4;                          // 0..255
    const float4* gw4 = (const float4*)gate_w;
    float4* gwT4 = (float4*)(ws + WS_GWT);
    gwT4[d4 * 16 + e] = gw4[e * 256 + d4];
    float* s_glob = ws + WS_SG;
    s_glob[gid] = 0.f;
    s_glob[gid + 4096] = 0.f;
}

// ---------------------------------------------------------------------------
// Fused: 1024 blocks x 256 thr, 8 tokens/block.
// A: x-tile -> LDS (coalesced, once); thread t owns d-cols 4t..4t+3 ->
//    x^2 column partials with no reduction needed.
// B: routing from LDS x (broadcast) + gwT (coalesced). Lane=(g tok, h half,
//    e expert): 512-d half dot, shfl_xor(16) completes logit.
// C: top2 shfl scan (stable, matches lax.top_k).
// D: combine; x from LDS, re rows L1-hot, coalesced float4 out.
// ---------------------------------------------------------------------------
__global__ __launch_bounds__(256, 4) void moe_fused(
    const float* __restrict__ x,
    const float* __restrict__ gate_b,
    const float* __restrict__ sh,
    const float* __restrict__ re,
    float* __restrict__ out,
    float* __restrict__ ws)
{
    __shared__ float xt[8][XROW];

    const int t = threadIdx.x;
    const int b = blockIdx.x;
    const float4* gwT4 = (const float4*)(ws + WS_GWT);
    float* s_glob = ws + WS_SG;

    // ---- A: stage 8 token rows, accumulate x^2 for owned d-columns ----
    float4 ss = make_float4(0.f, 0.f, 0.f, 0.f);
    {
        const float4* x4 = (const float4*)x + (size_t)b * 2048;
        #pragma unroll
        for (int i = 0; i < 8; ++i) {
            float4 v = x4[i * 256 + t];
            *(float4*)&xt[i][4 * t] = v;
            ss.x = fmaf(v.x, v.x, ss.x);
            ss.y = fmaf(v.y, v.y, ss.y);
            ss.z = fmaf(v.z, v.z, ss.z);
            ss.w = fmaf(v.w, v.w, ss.w);
        }
    }
    __syncthreads();

    const int lane = t & 63;
    const int wave = t >> 6;
    const int e = lane & 15;
    const int h = (lane >> 4) & 1;
    const int g = lane >> 5;

    // ---- B: routing ----
    const int tokL = wave * 2 + g;
    const float* xrow = &xt[tokL][h * 512];
    const float4* gt = gwT4 + h * 128 * 16;
    float4 a4 = make_float4(0.f, 0.f, 0.f, 0.f);
    #pragma unroll 8
    for (int i = 0; i < 128; ++i) {
        float4 xv = *(const float4*)(xrow + 4 * i);  // 4 distinct addrs, bcast
        float4 gv = gt[i * 16 + e];                  // 256B contiguous / 16 lanes
        a4.x = fmaf(xv.x, gv.x, a4.x);
        a4.y = fmaf(xv.y, gv.y, a4.y);
        a4.z = fmaf(xv.z, gv.z, a4.z);
        a4.w = fmaf(xv.w, gv.w, a4.w);
    }
    float acc = (a4.x + a4.y) + (a4.z + a4.w);
    acc += __shfl_xor(acc, 16, 64);                  // merge d-halves
    acc += gate_b[e];

    // ---- C: stable top2 scan in this token's 16 expert lanes ----
    float v0 = -3.0e38f, v1 = -3.0e38f;
    int i0 = 0, i1 = 0;
    const int base = lane & 32;
    #pragma unroll
    for (int j = 0; j < NEXP; ++j) {
        float lv = __shfl(acc, base + j, 64);
        if (lv > v0)      { v1 = v0; i1 = i0; v0 = lv; i0 = j; }
        else if (lv > v1) { v1 = lv; i1 = j; }
    }
    float ex = __expf(v1 - v0);                      // softmax denom cancels
    float w0 = 1.f / (1.f + ex);
    float w1 = ex * w0;

    // hoisted shared-expert column sum for combine slots
    float4 shs[4];
    {
        const float4* s0 = (const float4*)sh;
        const float4* s1 = (const float4*)(sh + DDIM);
        #pragma unroll
        for (int j = 0; j < 4; ++j) {
            float4 p = s0[lane + 64 * j];
            float4 q = s1[lane + 64 * j];
            shs[j] = make_float4(p.x + q.x, p.y + q.y, p.z + q.z, p.w + q.w);
        }
    }

    // ---- D: combine (x from LDS, coalesced out) ----
    #pragma unroll
    for (int tk = 0; tk < 2; ++tk) {
        const int src = tk << 5;
        float a0 = __shfl(w0, src, 64);
        float a1 = __shfl(w1, src, 64);
        int   e0 = __shfl(i0, src, 64);
        int   e1 = __shfl(i1, src, 64);
        const int tokL2 = wave * 2 + tk;
        const float4* xr = (const float4*)&xt[tokL2][0];
        const float4* r0 = (const float4*)(re + (size_t)e0 * DDIM);
        const float4* r1 = (const float4*)(re + (size_t)e1 * DDIM);
        float4* o = (float4*)(out + ((size_t)b * 8 + tokL2) * DDIM);
        #pragma unroll
        for (int j = 0; j < 4; ++j) {
            float4 xv = xr[lane + 64 * j];
            float4 b0 = r0[lane + 64 * j];
            float4 b1 = r1[lane + 64 * j];
            float4 r;
            r.x = xv.x * (shs[j].x + a0 * b0.x + a1 * b1.x);
            r.y = xv.y * (shs[j].y + a0 * b0.y + a1 * b1.y);
            r.z = xv.z * (shs[j].z + a0 * b0.z + a1 * b1.z);
            r.w = xv.w * (shs[j].w + a0 * b0.w + a1 * b1.w);
            o[lane + 64 * j] = r;
        }
    }

    // ---- x^2 partials: thread owns its 4 d-columns exclusively ----
    {
        float* rep = s_glob + (size_t)(b & (NREP - 1)) * DDIM;
        atomicAdd(&rep[4 * t + 0], ss.x);
        atomicAdd(&rep[4 * t + 1], ss.y);
        atomicAdd(&rep[4 * t + 2], ss.z);
        atomicAdd(&rep[4 * t + 3], ss.w);
    }
}

// ---------------------------------------------------------------------------
// Partial Gram: block b covers d-chunk [64b, 64b+64); writes G_part[b][136].
// ---------------------------------------------------------------------------
__global__ __launch_bounds__(320) void moe_div_partial(
    const float* __restrict__ re,
    const float* __restrict__ ws,
    float* __restrict__ G_part_unused)
{
    __shared__ float reT[64][17];
    __shared__ float s4[4][64];
    __shared__ float s_loc[64];

    const int t = threadIdx.x;
    const int b = blockIdx.x;
    const int d0 = b * 64;
    const float* s_glob = ws + WS_SG;
    float* G_part = (float*)(ws + WS_GP);

    if (t < 256) {
        // s_glob replica reduce (2 reps per thread-row)
        int c = t & 63, r = t >> 6;
        s4[r][c] = s_glob[r * DDIM + d0 + c] + s_glob[(r + 4) * DDIM + d0 + c];
        // stage re chunk transposed
        int e = t >> 4, d4 = t & 15;
        float4 v = ((const float4*)(re + (size_t)e * DDIM + d0))[d4];
        reT[d4 * 4 + 0][e] = v.x;
        reT[d4 * 4 + 1][e] = v.y;
        reT[d4 * 4 + 2][e] = v.z;
        reT[d4 * 4 + 3][e] = v.w;
    }
    __syncthreads();
    if (t < 64) s_loc[t] = (s4[0][t] + s4[1][t]) + (s4[2][t] + s4[3][t]);
    __syncthreads();

    const int p = t >> 1;
    const int half = t & 1;
    float a = 0.f;
    int pe = 0, pf = 0;
    if (p < NPAIR) {
        int rem = p;
        while (rem >= NEXP - pe) { rem -= NEXP - pe; ++pe; }
        pf = pe + rem;
        #pragma unroll
        for (int i = 0; i < 32; ++i) {
            int dd = half * 32 + i;
            a += s_loc[dd] * reT[dd][pe] * reT[dd][pf];
        }
    }
    a += __shfl_down(a, 1, 64);
    if (p < NPAIR && half == 0) G_part[b * NPAIR + p] = a;
}

// ---------------------------------------------------------------------------
// Finalize: sum 16 partial Grams, norms, clipped cosine mean * lambda.
// ---------------------------------------------------------------------------
__global__ __launch_bounds__(192) void moe_div_final(
    const float* __restrict__ ws,
    float* __restrict__ div_out)
{
    __shared__ float G[NPAIR];
    __shared__ float nr[NEXP];
    __shared__ float lsum;
    const float* G_part = ws + WS_GP;
    const int t = threadIdx.x;

    if (t == 0) lsum = 0.f;
    if (t < NPAIR) {
        float g = 0.f;
        #pragma unroll
        for (int b = 0; b < 16; ++b) g += G_part[b * NPAIR + t];
        G[t] = g;
    }
    __syncthreads();
    if (t < NEXP) {
        int idx = t * NEXP - (t * (t - 1)) / 2;   // diagonal (t,t)
        nr[t] = fmaxf(sqrtf(G[idx]), 1e-8f);
    }
    __syncthreads();
    if (t < NPAIR) {
        int pe = 0, rem = t;
        while (rem >= NEXP - pe) { rem -= NEXP - pe; ++pe; }
        int pf = pe + rem;
        if (pe != pf) {
            float sim = G[t] / (nr[pe] * nr[pf]);
            sim = fminf(1.f, fmaxf(-1.f, sim));
            atomicAdd(&lsum, 2.f * sim);
        }
    }
    __syncthreads();
    if (t == 0) *div_out = lsum / (float)(NEXP * (NEXP - 1)) * 0.1f;
}

extern "C" void kernel_launch(void* const* d_in, const int* in_sizes, int n_in,
                              void* d_out, int out_size, void* d_ws, size_t ws_size,
                              hipStream_t stream) {
    const float* x  = (const float*)d_in[0];
    const float* gw = (const float*)d_in[1];
    const float* gb = (const float*)d_in[2];
    const float* sh = (const float*)d_in[3];
    const float* re = (const float*)d_in[4];
    float* out = (float*)d_out;
    float* ws = (float*)d_ws;   // needs (16384 + 8*1024 + 16*136)*4 ~= 107 KB

    moe_prep<<<16, 256, 0, stream>>>(gw, ws);
    moe_fused<<<1024, 256, 0, stream>>>(x, gb, sh, re, out, ws);
    moe_div_partial<<<16, 320, 0, stream>>>(re, ws, nullptr);
    moe_div_final<<<1, 192, 0, stream>>>(ws, out + (size_t)NTOK * DDIM);
}